// Round 17
// baseline (180.202 us; speedup 1.0000x reference)
//
#include <hip/hip_runtime.h>
#include <cstdint>
#include <cstddef>

typedef __bf16 bf16_t;
typedef bf16_t bf16x8 __attribute__((ext_vector_type(8)));
typedef bf16_t bf16x4 __attribute__((ext_vector_type(4)));
typedef float  f32x4  __attribute__((ext_vector_type(4)));

#define MFMA16(a, b, c) __builtin_amdgcn_mfma_f32_16x16x32_bf16((a), (b), (c), 0, 0, 0)

// async global->LDS DMA, 16B/lane; LDS dest = wave-uniform base + lane*16.
// offset is ALWAYS 0 (the imm offset does NOT apply to the global address on the
// LDS-DMA path — round-10/11 lesson) — all offsets baked into pointers.
#define GLOAD16(GP, LP)                                                           \
    __builtin_amdgcn_global_load_lds(                                             \
        (const __attribute__((address_space(1))) unsigned int*)(GP),              \
        (__attribute__((address_space(3))) unsigned int*)(LP), 16, 0, 0)

static constexpr int Bb = 2, Ss = 2048, Hh = 16, Dd = 128, DH = 2048;
// 1/sqrt(128) * log2(e): softmax runs in the exp2 domain (native v_exp_f32)
static constexpr float QSCALE = 0.08838834764831845f * 1.4426950408889634f;

// ---------------- merged prep: x->bf16 convert + 4 weight transposes ----------------
__global__ __launch_bounds__(256) void k_prep(
    const float* __restrict__ x,
    const float* __restrict__ Wq, const float* __restrict__ Wk,
    const float* __restrict__ Wv, const float* __restrict__ Wo,
    bf16_t* __restrict__ xb, bf16_t* __restrict__ Wt, bf16_t* __restrict__ Wot) {
    __shared__ float t[32][33];
    const int tid = threadIdx.x;
    const int bid = blockIdx.x;
    if (bid < 512) {
        int i = (bid * 256 + tid) * 4;
        float4 v = *reinterpret_cast<const float4*>(x + i);
        bf16x4 o;
        o[0] = (bf16_t)v.x; o[1] = (bf16_t)v.y; o[2] = (bf16_t)v.z; o[3] = (bf16_t)v.w;
        *reinterpret_cast<bf16x4*>(xb + i) = o;
        return;
    }
    const int u = bid - 512, m = u >> 8, tt = u & 255;
    const float* src; bf16_t* dst; int R, C, bx, by;
    if (m < 3) { src = (m == 0) ? Wq : (m == 1) ? Wk : Wv; dst = Wt + (size_t)m * 262144;
                 R = 128;  C = 2048; bx = tt & 63, by = tt >> 6; }
    else       { src = Wo; dst = Wot;
                 R = 2048; C = 128;  bx = tt & 3,  by = tt >> 2; }
    const int tx = tid & 31, ty = tid >> 5;
    const int c0 = bx * 32, r0 = by * 32;
#pragma unroll
    for (int i = 0; i < 4; i++)
        t[ty + i * 8][tx] = src[(size_t)(r0 + ty + i * 8) * C + c0 + tx];
    __syncthreads();
#pragma unroll
    for (int i = 0; i < 4; i++)
        dst[(size_t)(c0 + ty + i * 8) * R + r0 + tx] = (bf16_t)t[tx][ty + i * 8];
}

// ---------------- QKV projection GEMM: W staged once (swizzled), A direct from global ----------------
__global__ __launch_bounds__(256) void k_qkv(
    const bf16_t* __restrict__ xb, const bf16_t* __restrict__ Wt,
    const float* __restrict__ bq, const float* __restrict__ bk, const float* __restrict__ bv,
    bf16_t* __restrict__ Qw, bf16_t* __restrict__ Kw, bf16_t* __restrict__ Vw) {
    __shared__ bf16_t smem[17408];                 // Bs uses first 16384; epilogue reuses all
    bf16_t* Bs = smem;                             // [128 n][128 k] XOR-swizzled 16B blocks

    const int tid = threadIdx.x;
    const int w = tid >> 6, lane = tid & 63, c = lane & 15, g = lane >> 4;
    const int cm = c & 7;
    const int m0 = blockIdx.x * 128, n0g = blockIdx.y * 128, z = blockIdx.z;
    const bf16_t* Wz = Wt + (size_t)z * DH * Dd;
    const int wm = w * 32;

    // stage full W-tile once: 128x128 bf16, dest block ^= (row&7)
#pragma unroll
    for (int i = 0; i < 8; i++) {
        int e = tid + i * 256; int row = e >> 4, bg = e & 15;
        *reinterpret_cast<uint4*>(&Bs[row * 128 + ((bg ^ (row & 7)) * 8)]) =
            *reinterpret_cast<const uint4*>(&Wz[(size_t)(n0g + row) * 128 + bg * 8]);
    }
    __syncthreads();

    f32x4 acc[2][8];
#pragma unroll
    for (int a = 0; a < 2; a++)
#pragma unroll
        for (int b = 0; b < 8; b++) acc[a][b] = f32x4{0.f, 0.f, 0.f, 0.f};

    const int ar0 = m0 + wm + c;
#pragma unroll
    for (int kb = 0; kb < 4; kb++) {
        bf16x8 af0 = *reinterpret_cast<const bf16x8*>(&xb[(size_t)ar0 * 128 + kb * 32 + g * 8]);
        bf16x8 af1 = *reinterpret_cast<const bf16x8*>(&xb[(size_t)(ar0 + 16) * 128 + kb * 32 + g * 8]);
#pragma unroll
        for (int nb = 0; nb < 8; nb++) {
            bf16x8 bfr = *reinterpret_cast<const bf16x8*>(
                &Bs[(nb * 16 + c) * 128 + (((4 * kb + g) ^ cm) * 8)]);
            acc[0][nb] = MFMA16(af0, bfr, acc[0][nb]);
            acc[1][nb] = MFMA16(af1, bfr, acc[1][nb]);
        }
    }

    const float* bias = (z == 0) ? bq : (z == 1) ? bk : bv;
    const float sc = (z == 0) ? QSCALE : 1.0f;
    const int cstride = (z == 2) ? 131 : 136;
    __syncthreads();
#pragma unroll
    for (int mb = 0; mb < 2; mb++)
#pragma unroll
        for (int nb = 0; nb < 8; nb++) {
            float bs = bias[n0g + nb * 16 + c];
#pragma unroll
            for (int r = 0; r < 4; r++) {
                int row = wm + mb * 16 + g * 4 + r;
                int col = nb * 16 + c;
                smem[row * cstride + col] = (bf16_t)((acc[mb][nb][r] + bs) * sc);
            }
        }
    __syncthreads();
    const int h = blockIdx.y;
    if (z <= 1) {
        bf16_t* O = z ? Kw : Qw;
#pragma unroll
        for (int i = 0; i < 8; i++) {
            int e = tid + i * 256; int row = e >> 4, col = (e & 15) * 8;
            int sg = m0 + row, b = sg >> 11, s2 = sg & 2047;
            *reinterpret_cast<uint4*>(&O[(((size_t)(b * Hh + h)) * Ss + s2) * Dd + col]) =
                *reinterpret_cast<const uint4*>(&smem[row * 136 + col]);
        }
    } else {
        int b = m0 >> 11; int sbase = m0 & 2047;
        const unsigned short* cs16 = reinterpret_cast<const unsigned short*>(smem);
#pragma unroll
        for (int i = 0; i < 32; i++) {
            int e = tid + i * 256; int d = e >> 6, sl2 = (e & 63) * 2;
            unsigned int lo = cs16[sl2 * 131 + d], hi = cs16[(sl2 + 1) * 131 + d];
            unsigned int pk = lo | (hi << 16);
            *reinterpret_cast<unsigned int*>(
                &Vw[(((size_t)(b * Hh + h)) * Dd + d) * Ss + sbase + sl2]) = pk;
        }
    }
}

// ---- softmax for one 16-row q-block; writes P into XOR-swizzled PbF ----
#define SOFTMAX_HALF(SACC, M_RUN, L_RUN, AO, PROW)                                   \
    do {                                                                             \
        float pm = fmaxf(fmaxf(SACC[0][0], SACC[0][1]), fmaxf(SACC[0][2], SACC[0][3])); \
        _Pragma("unroll")                                                            \
        for (int nb = 1; nb < 4; nb++)                                               \
            _Pragma("unroll")                                                        \
            for (int r = 0; r < 4; r++) pm = fmaxf(pm, SACC[nb][r]);                 \
        pm = fmaxf(pm, __shfl_xor(pm, 16));                                          \
        pm = fmaxf(pm, __shfl_xor(pm, 32));                                          \
        if (!__all(pm <= M_RUN + 11.5f)) {                                           \
            float mn_ = fmaxf(M_RUN, pm);                                            \
            float sc_ = exp2f(M_RUN - mn_);                                          \
            M_RUN = mn_;                                                             \
            L_RUN *= sc_;                                                            \
            _Pragma("unroll")                                                        \
            for (int r = 0; r < 4; r++) {                                            \
                float s4_ = __shfl(sc_, g * 4 + r);                                  \
                _Pragma("unroll")                                                    \
                for (int db = 0; db < 8; db++) AO[db][r] *= s4_;                     \
            }                                                                        \
        }                                                                            \
        float rs_ = 0.f;                                                             \
        _Pragma("unroll")                                                            \
        for (int nb = 0; nb < 4; nb++) {                                             \
            bf16x4 pk_;                                                              \
            _Pragma("unroll")                                                        \
            for (int r = 0; r < 4; r++) {                                            \
                float pe_ = exp2f(SACC[nb][r] - M_RUN);                              \
                rs_ += pe_;                                                          \
                pk_[r] = (bf16_t)pe_;                                                \
            }                                                                        \
            *reinterpret_cast<bf16x4*>(                                              \
                &PbF[(PROW) * 64 + (((2 * nb + (g >> 1)) ^ cm) * 8) + (g & 1) * 4]) = pk_; \
        }                                                                            \
        L_RUN += rs_;                                                                \
    } while (0)

// ---------------- flash attention: 48 KB LDS -> 3 blocks/CU ----------------
// Single K buffer; K(t+1) prefetched into 4 named registers at tile top (T14),
// ds_written (swizzled dest) right after the mid-tile barrier — safe because all
// waves have completed QK^T reads of tile t by then. V stays gload_lds with
// pre-swizzled source. Both sync points are full __syncthreads() (order-robust).
__global__ __launch_bounds__(256, 3) void k_attn(
    const bf16_t* __restrict__ Qw, const bf16_t* __restrict__ Kw,
    const bf16_t* __restrict__ Vw, bf16_t* __restrict__ AO) {
    __shared__ bf16_t smem[24576];               // 48 KB
    bf16_t* KtF = smem;                          // K  [64][128] swz
    bf16_t* VtF = smem + 8192;                   // V^T[128][64] swz
    bf16_t* PbF = smem + 16384;                  // P  [128][64] swz

    const int tid = threadIdx.x;
    const int w = tid >> 6, lane = tid & 63, c = lane & 15, g = lane >> 4;
    const int cm = c & 7;

    const int f = blockIdx.x;                    // bijective XCD swizzle (512 % 8 == 0)
    const int wid = (f & 7) * 64 + (f >> 3);
    const int bh = wid >> 4, q0 = (wid & 15) * 128;

    const bf16_t* Qb = Qw + (size_t)bh * Ss * Dd;
    const bf16_t* Kb = Kw + (size_t)bh * Ss * Dd;
    const bf16_t* Vb = Vw + (size_t)bh * Dd * Ss;

    bf16x8 qlo[4], qhi[4];
    const int qrl = q0 + w * 32 + c, qrh = qrl + 16;
#pragma unroll
    for (int kb = 0; kb < 4; kb++) {
        qlo[kb] = *reinterpret_cast<const bf16x8*>(&Qb[(size_t)qrl * Dd + kb * 32 + g * 8]);
        qhi[kb] = *reinterpret_cast<const bf16x8*>(&Qb[(size_t)qrh * Dd + kb * 32 + g * 8]);
    }

    f32x4 aolo[8], aohi[8];
#pragma unroll
    for (int i = 0; i < 8; i++) { aolo[i] = f32x4{0.f,0.f,0.f,0.f}; aohi[i] = f32x4{0.f,0.f,0.f,0.f}; }
    float m_lo = -1e30f, l_lo = 0.f, m_hi = -1e30f, l_hi = 0.f;

    // K staging (reg path): lane covers rows w*16+krow+{0,4,8,12}, col block kcb
    const int krow = lane >> 4;                         // 0..3
    const int kcb  = lane & 15;                         // 0..15
    const bf16_t* ksrc = Kb + (w * 16 + krow) * 128 + kcb * 8;   // +512/row-quad, +8192/tile
    // constant swizzled LDS dests: dest block = kcb ^ ((row)&7)
    bf16_t* kd0 = KtF + (w * 16 + krow +  0) * 128 + ((kcb ^ ( krow      & 7)) * 8);
    bf16_t* kd1 = KtF + (w * 16 + krow +  4) * 128 + ((kcb ^ ((krow + 4) & 7)) * 8);
    bf16_t* kd2 = KtF + (w * 16 + krow +  8) * 128 + ((kcb ^ ( krow      & 7)) * 8);
    bf16_t* kd3 = KtF + (w * 16 + krow + 12) * 128 + ((kcb ^ ((krow + 4) & 7)) * 8);

    // V staging (gload_lds, pre-swizzled source): lane L -> LDS base + 16*L
    const int vrl = lane >> 3;                          // 0..7
    const int vc0 = ((lane & 7) ^ vrl) * 8;
    const bf16_t* vsrc = Vb + (w * 32 + vrl) * 2048 + vc0;
    const unsigned wq = __builtin_amdgcn_readfirstlane((unsigned)(w * 2048));
    bf16_t* vd = VtF + wq;

    // prologue: stage K(0) via regs + ds_write
    {
        uint4 k0 = *reinterpret_cast<const uint4*>(ksrc);
        uint4 k1 = *reinterpret_cast<const uint4*>(ksrc + 512);
        uint4 k2 = *reinterpret_cast<const uint4*>(ksrc + 1024);
        uint4 k3 = *reinterpret_cast<const uint4*>(ksrc + 1536);
        *reinterpret_cast<uint4*>(kd0) = k0;
        *reinterpret_cast<uint4*>(kd1) = k1;
        *reinterpret_cast<uint4*>(kd2) = k2;
        *reinterpret_cast<uint4*>(kd3) = k3;
        ksrc += 8192;
    }
    __syncthreads();

    for (int t = 0; t < 32; ++t) {
        // issue V(t) DMA + K(t+1) reg loads (both in flight through QK^T+softmax)
        GLOAD16(vsrc,         vd);
        GLOAD16(vsrc + 16384, vd + 512);    // +8 V rows
        GLOAD16(vsrc + 32768, vd + 1024);   // +16
        GLOAD16(vsrc + 49152, vd + 1536);   // +24
        vsrc += 64;
        uint4 kp0, kp1, kp2, kp3;
        if (t < 31) {
            kp0 = *reinterpret_cast<const uint4*>(ksrc);
            kp1 = *reinterpret_cast<const uint4*>(ksrc + 512);
            kp2 = *reinterpret_cast<const uint4*>(ksrc + 1024);
            kp3 = *reinterpret_cast<const uint4*>(ksrc + 1536);
            ksrc += 8192;
        }

        // ---- QK^T from KtF ----
        f32x4 slo[4], shi[4];
#pragma unroll
        for (int nb = 0; nb < 4; nb++) { slo[nb] = f32x4{0.f,0.f,0.f,0.f}; shi[nb] = f32x4{0.f,0.f,0.f,0.f}; }
        __builtin_amdgcn_s_setprio(1);
#pragma unroll
        for (int kb = 0; kb < 4; kb++)
#pragma unroll
            for (int nb = 0; nb < 4; nb++) {
                bf16x8 kf = *reinterpret_cast<const bf16x8*>(
                    &KtF[(nb * 16 + c) * 128 + ((4 * kb + g) ^ cm) * 8]);
                slo[nb] = MFMA16(kf, qlo[kb], slo[nb]);
                shi[nb] = MFMA16(kf, qhi[kb], shi[nb]);
            }
        __builtin_amdgcn_s_setprio(0);

        // ---- online softmax (exp2 domain) ----
        SOFTMAX_HALF(slo, m_lo, l_lo, aolo, w * 32 + c);
        SOFTMAX_HALF(shi, m_hi, l_hi, aohi, w * 32 + 16 + c);

        // mid-tile: V(t) + K(t+1) regs landed; all waves done with KtF reads
        __syncthreads();

        // overwrite KtF with K(t+1) (safe: QK^T reads complete block-wide)
        if (t < 31) {
            *reinterpret_cast<uint4*>(kd0) = kp0;
            *reinterpret_cast<uint4*>(kd1) = kp1;
            *reinterpret_cast<uint4*>(kd2) = kp2;
            *reinterpret_cast<uint4*>(kd3) = kp3;
        }

        // ---- PV (PbF own-wave reads; VtF staged this tile) ----
        bf16x8 plo[2], phi[2];
#pragma unroll
        for (int kb2 = 0; kb2 < 2; kb2++) {
            plo[kb2] = *reinterpret_cast<const bf16x8*>(
                &PbF[(w * 32 + c) * 64 + ((4 * kb2 + g) ^ cm) * 8]);
            phi[kb2] = *reinterpret_cast<const bf16x8*>(
                &PbF[(w * 32 + 16 + c) * 64 + ((4 * kb2 + g) ^ cm) * 8]);
        }
        __builtin_amdgcn_s_setprio(1);
#pragma unroll
        for (int db = 0; db < 8; db++)
#pragma unroll
            for (int kb2 = 0; kb2 < 2; kb2++) {
                bf16x8 vf = *reinterpret_cast<const bf16x8*>(
                    &VtF[(db * 16 + c) * 64 + ((4 * kb2 + g) ^ cm) * 8]);
                aolo[db] = MFMA16(plo[kb2], vf, aolo[db]);
                aohi[db] = MFMA16(phi[kb2], vf, aohi[db]);
            }
        __builtin_amdgcn_s_setprio(0);

        // end of tile: K ds_writes visible to all; V reads complete before next issue
        __syncthreads();
    }

    // epilogue: reduce l, normalize, coalesced write
    l_lo += __shfl_xor(l_lo, 16); l_lo += __shfl_xor(l_lo, 32);
    l_hi += __shfl_xor(l_hi, 16); l_hi += __shfl_xor(l_hi, 32);
    float ilo = 1.0f / l_lo, ihi = 1.0f / l_hi;
    bf16_t (*Os)[136] = reinterpret_cast<bf16_t(*)[136]>(smem);
#pragma unroll
    for (int r = 0; r < 4; r++) {
        float i4l = __shfl(ilo, g * 4 + r);
        float i4h = __shfl(ihi, g * 4 + r);
        int rowl = w * 32 + g * 4 + r, rowh = rowl + 16;
#pragma unroll
        for (int db = 0; db < 8; db++) {
            Os[rowl][db * 16 + c] = (bf16_t)(aolo[db][r] * i4l);
            Os[rowh][db * 16 + c] = (bf16_t)(aohi[db][r] * i4h);
        }
    }
    __syncthreads();
    const int b = bh >> 4, h = bh & 15;
#pragma unroll
    for (int i = 0; i < 8; i++) {
        int e = tid + i * 256; int row = e >> 4, col = (e & 15) * 8;
        *reinterpret_cast<uint4*>(&AO[((size_t)(b * Ss + q0 + row)) * DH + h * Dd + col]) =
            *reinterpret_cast<const uint4*>(&Os[row][col]);
    }
}

// ---------------- output projection v5: 512 blocks x 4 waves, 4 acc chains ----------------
__global__ __launch_bounds__(256) void k_outproj(
    const bf16_t* __restrict__ A, const bf16_t* __restrict__ Wot,
    const float* __restrict__ bo, float* __restrict__ out) {
    const int tid = threadIdx.x;
    const int w = tid >> 6, lane = tid & 63, c = lane & 15, g = lane >> 4;
    const int mt = blockIdx.x >> 1, nh = blockIdx.x & 1;
    const int m0 = mt * 16;
    const int nb = nh * 4 + w;                 // global 16-col block, 0..7

    f32x4 a0 = f32x4{0.f,0.f,0.f,0.f}, a1 = f32x4{0.f,0.f,0.f,0.f};
    f32x4 a2 = f32x4{0.f,0.f,0.f,0.f}, a3 = f32x4{0.f,0.f,0.f,0.f};

    const bf16_t* Ab = A   + (size_t)(m0 + c) * DH + g * 8;
    const bf16_t* Bw = Wot + (size_t)(nb * 16 + c) * DH + g * 8;

#pragma unroll 4
    for (int kk = 0; kk < 64; kk += 4) {
        bf16x8 af0  = *reinterpret_cast<const bf16x8*>(Ab + (kk + 0) * 32);
        bf16x8 bf0  = *reinterpret_cast<const bf16x8*>(Bw + (kk + 0) * 32);
        bf16x8 af1  = *reinterpret_cast<const bf16x8*>(Ab + (kk + 1) * 32);
        bf16x8 bf1  = *reinterpret_cast<const bf16x8*>(Bw + (kk + 1) * 32);
        bf16x8 af2  = *reinterpret_cast<const bf16x8*>(Ab + (kk + 2) * 32);
        bf16x8 bf2  = *reinterpret_cast<const bf16x8*>(Bw + (kk + 2) * 32);
        bf16x8 af3  = *reinterpret_cast<const bf16x8*>(Ab + (kk + 3) * 32);
        bf16x8 bf3  = *reinterpret_cast<const bf16x8*>(Bw + (kk + 3) * 32);
        a0 = MFMA16(af0, bf0, a0);
        a1 = MFMA16(af1, bf1, a1);
        a2 = MFMA16(af2, bf2, a2);
        a3 = MFMA16(af3, bf3, a3);
    }

    f32x4 acc = (a0 + a1) + (a2 + a3);

    float bs = bo[nb * 16 + c];
#pragma unroll
    for (int r = 0; r < 4; r++)
        out[(size_t)(m0 + g * 4 + r) * Dd + nb * 16 + c] = acc[r] + bs;
}

// ---------------- launcher ----------------
extern "C" void kernel_launch(void* const* d_in, const int* in_sizes, int n_in,
                              void* d_out, int out_size, void* d_ws, size_t ws_size,
                              hipStream_t stream) {
    const float* x  = (const float*)d_in[0];
    const float* Wq = (const float*)d_in[1];
    const float* bq = (const float*)d_in[2];
    const float* Wk = (const float*)d_in[3];
    const float* bk = (const float*)d_in[4];
    const float* Wv = (const float*)d_in[5];
    const float* bv = (const float*)d_in[6];
    const float* Wo = (const float*)d_in[7];
    const float* bo = (const float*)d_in[8];
    float* out = (float*)d_out;

    char* ws = (char*)d_ws;
    bf16_t* xb  = (bf16_t*)(ws);
    bf16_t* Wt  = (bf16_t*)(ws + 1048576);
    bf16_t* Wot = (bf16_t*)(ws + 2621440);
    bf16_t* Qw  = (bf16_t*)(ws + 3145728);
    bf16_t* Kw  = (bf16_t*)(ws + 3145728 + 16777216);
    bf16_t* Vw  = (bf16_t*)(ws + 3145728 + 2 * 16777216);
    bf16_t* AO  = (bf16_t*)(ws + 3145728 + 3 * 16777216);

    k_prep<<<1536, 256, 0, stream>>>(x, Wq, Wk, Wv, Wo, xb, Wt, Wot);
    k_qkv<<<dim3(32, 16, 3), 256, 0, stream>>>(xb, Wt, bq, bk, bv, Qw, Kw, Vw);
    k_attn<<<512, 256, 0, stream>>>(Qw, Kw, Vw, AO);
    k_outproj<<<512, 256, 0, stream>>>(AO, Wot, bo, out);
}

// Round 18
// 151.050 us; speedup vs baseline: 1.1930x; 1.1930x over previous
//
#include <hip/hip_runtime.h>
#include <cstdint>
#include <cstddef>

typedef __bf16 bf16_t;
typedef bf16_t bf16x8 __attribute__((ext_vector_type(8)));
typedef bf16_t bf16x4 __attribute__((ext_vector_type(4)));
typedef float  f32x4  __attribute__((ext_vector_type(4)));

#define MFMA16(a, b, c) __builtin_amdgcn_mfma_f32_16x16x32_bf16((a), (b), (c), 0, 0, 0)

// async global->LDS DMA, 16B/lane; LDS dest = wave-uniform base + lane*16.
// offset is ALWAYS 0 (the imm offset does NOT apply to the global address on the
// LDS-DMA path — round-10/11 lesson) — all offsets baked into pointers.
#define GLOAD16(GP, LP)                                                           \
    __builtin_amdgcn_global_load_lds(                                             \
        (const __attribute__((address_space(1))) unsigned int*)(GP),              \
        (__attribute__((address_space(3))) unsigned int*)(LP), 16, 0, 0)

static constexpr int Bb = 2, Ss = 2048, Hh = 16, Dd = 128, DH = 2048;
// 1/sqrt(128) * log2(e): softmax runs in the exp2 domain (native v_exp_f32)
static constexpr float QSCALE = 0.08838834764831845f * 1.4426950408889634f;

// ---------------- merged prep: x->bf16 convert + 4 weight transposes ----------------
__global__ __launch_bounds__(256) void k_prep(
    const float* __restrict__ x,
    const float* __restrict__ Wq, const float* __restrict__ Wk,
    const float* __restrict__ Wv, const float* __restrict__ Wo,
    bf16_t* __restrict__ xb, bf16_t* __restrict__ Wt, bf16_t* __restrict__ Wot) {
    __shared__ float t[32][33];
    const int tid = threadIdx.x;
    const int bid = blockIdx.x;
    if (bid < 512) {
        int i = (bid * 256 + tid) * 4;
        float4 v = *reinterpret_cast<const float4*>(x + i);
        bf16x4 o;
        o[0] = (bf16_t)v.x; o[1] = (bf16_t)v.y; o[2] = (bf16_t)v.z; o[3] = (bf16_t)v.w;
        *reinterpret_cast<bf16x4*>(xb + i) = o;
        return;
    }
    const int u = bid - 512, m = u >> 8, tt = u & 255;
    const float* src; bf16_t* dst; int R, C, bx, by;
    if (m < 3) { src = (m == 0) ? Wq : (m == 1) ? Wk : Wv; dst = Wt + (size_t)m * 262144;
                 R = 128;  C = 2048; bx = tt & 63, by = tt >> 6; }
    else       { src = Wo; dst = Wot;
                 R = 2048; C = 128;  bx = tt & 3,  by = tt >> 2; }
    const int tx = tid & 31, ty = tid >> 5;
    const int c0 = bx * 32, r0 = by * 32;
#pragma unroll
    for (int i = 0; i < 4; i++)
        t[ty + i * 8][tx] = src[(size_t)(r0 + ty + i * 8) * C + c0 + tx];
    __syncthreads();
#pragma unroll
    for (int i = 0; i < 4; i++)
        dst[(size_t)(c0 + ty + i * 8) * R + r0 + tx] = (bf16_t)t[tx][ty + i * 8];
}

// ---------------- QKV projection GEMM: W staged once (swizzled), A direct from global ----------------
__global__ __launch_bounds__(256) void k_qkv(
    const bf16_t* __restrict__ xb, const bf16_t* __restrict__ Wt,
    const float* __restrict__ bq, const float* __restrict__ bk, const float* __restrict__ bv,
    bf16_t* __restrict__ Qw, bf16_t* __restrict__ Kw, bf16_t* __restrict__ Vw) {
    __shared__ bf16_t smem[17408];                 // Bs uses first 16384; epilogue reuses all
    bf16_t* Bs = smem;                             // [128 n][128 k] XOR-swizzled 16B blocks

    const int tid = threadIdx.x;
    const int w = tid >> 6, lane = tid & 63, c = lane & 15, g = lane >> 4;
    const int cm = c & 7;
    const int m0 = blockIdx.x * 128, n0g = blockIdx.y * 128, z = blockIdx.z;
    const bf16_t* Wz = Wt + (size_t)z * DH * Dd;
    const int wm = w * 32;

    // stage full W-tile once: 128x128 bf16, dest block ^= (row&7)
#pragma unroll
    for (int i = 0; i < 8; i++) {
        int e = tid + i * 256; int row = e >> 4, bg = e & 15;
        *reinterpret_cast<uint4*>(&Bs[row * 128 + ((bg ^ (row & 7)) * 8)]) =
            *reinterpret_cast<const uint4*>(&Wz[(size_t)(n0g + row) * 128 + bg * 8]);
    }
    __syncthreads();

    f32x4 acc[2][8];
#pragma unroll
    for (int a = 0; a < 2; a++)
#pragma unroll
        for (int b = 0; b < 8; b++) acc[a][b] = f32x4{0.f, 0.f, 0.f, 0.f};

    const int ar0 = m0 + wm + c;
#pragma unroll
    for (int kb = 0; kb < 4; kb++) {
        bf16x8 af0 = *reinterpret_cast<const bf16x8*>(&xb[(size_t)ar0 * 128 + kb * 32 + g * 8]);
        bf16x8 af1 = *reinterpret_cast<const bf16x8*>(&xb[(size_t)(ar0 + 16) * 128 + kb * 32 + g * 8]);
#pragma unroll
        for (int nb = 0; nb < 8; nb++) {
            bf16x8 bfr = *reinterpret_cast<const bf16x8*>(
                &Bs[(nb * 16 + c) * 128 + (((4 * kb + g) ^ cm) * 8)]);
            acc[0][nb] = MFMA16(af0, bfr, acc[0][nb]);
            acc[1][nb] = MFMA16(af1, bfr, acc[1][nb]);
        }
    }

    const float* bias = (z == 0) ? bq : (z == 1) ? bk : bv;
    const float sc = (z == 0) ? QSCALE : 1.0f;
    const int cstride = (z == 2) ? 131 : 136;
    __syncthreads();
#pragma unroll
    for (int mb = 0; mb < 2; mb++)
#pragma unroll
        for (int nb = 0; nb < 8; nb++) {
            float bs = bias[n0g + nb * 16 + c];
#pragma unroll
            for (int r = 0; r < 4; r++) {
                int row = wm + mb * 16 + g * 4 + r;
                int col = nb * 16 + c;
                smem[row * cstride + col] = (bf16_t)((acc[mb][nb][r] + bs) * sc);
            }
        }
    __syncthreads();
    const int h = blockIdx.y;
    if (z <= 1) {
        bf16_t* O = z ? Kw : Qw;
#pragma unroll
        for (int i = 0; i < 8; i++) {
            int e = tid + i * 256; int row = e >> 4, col = (e & 15) * 8;
            int sg = m0 + row, b = sg >> 11, s2 = sg & 2047;
            *reinterpret_cast<uint4*>(&O[(((size_t)(b * Hh + h)) * Ss + s2) * Dd + col]) =
                *reinterpret_cast<const uint4*>(&smem[row * 136 + col]);
        }
    } else {
        int b = m0 >> 11; int sbase = m0 & 2047;
        const unsigned short* cs16 = reinterpret_cast<const unsigned short*>(smem);
#pragma unroll
        for (int i = 0; i < 32; i++) {
            int e = tid + i * 256; int d = e >> 6, sl2 = (e & 63) * 2;
            unsigned int lo = cs16[sl2 * 131 + d], hi = cs16[(sl2 + 1) * 131 + d];
            unsigned int pk = lo | (hi << 16);
            *reinterpret_cast<unsigned int*>(
                &Vw[(((size_t)(b * Hh + h)) * Dd + d) * Ss + sbase + sl2]) = pk;
        }
    }
}

// ---- softmax for one 16-row q-block; writes P into XOR-swizzled PbF ----
#define SOFTMAX_HALF(SACC, M_RUN, L_RUN, AO, PROW)                                   \
    do {                                                                             \
        float pm = fmaxf(fmaxf(SACC[0][0], SACC[0][1]), fmaxf(SACC[0][2], SACC[0][3])); \
        _Pragma("unroll")                                                            \
        for (int nb = 1; nb < 4; nb++)                                               \
            _Pragma("unroll")                                                        \
            for (int r = 0; r < 4; r++) pm = fmaxf(pm, SACC[nb][r]);                 \
        pm = fmaxf(pm, __shfl_xor(pm, 16));                                          \
        pm = fmaxf(pm, __shfl_xor(pm, 32));                                          \
        if (!__all(pm <= M_RUN + 11.5f)) {                                           \
            float mn_ = fmaxf(M_RUN, pm);                                            \
            float sc_ = exp2f(M_RUN - mn_);                                          \
            M_RUN = mn_;                                                             \
            L_RUN *= sc_;                                                            \
            _Pragma("unroll")                                                        \
            for (int r = 0; r < 4; r++) {                                            \
                float s4_ = __shfl(sc_, g * 4 + r);                                  \
                _Pragma("unroll")                                                    \
                for (int db = 0; db < 8; db++) AO[db][r] *= s4_;                     \
            }                                                                        \
        }                                                                            \
        float rs_ = 0.f;                                                             \
        _Pragma("unroll")                                                            \
        for (int nb = 0; nb < 4; nb++) {                                             \
            bf16x4 pk_;                                                              \
            _Pragma("unroll")                                                        \
            for (int r = 0; r < 4; r++) {                                            \
                float pe_ = exp2f(SACC[nb][r] - M_RUN);                              \
                rs_ += pe_;                                                          \
                pk_[r] = (bf16_t)pe_;                                                \
            }                                                                        \
            *reinterpret_cast<bf16x4*>(                                              \
                &PbF[(PROW) * 64 + (((2 * nb + (g >> 1)) ^ cm) * 8) + (g & 1) * 4]) = pk_; \
        }                                                                            \
        L_RUN += rs_;                                                                \
    } while (0)

// ---------------- flash attention: counted-vmcnt pipeline (T3/T4) ----------------
// Per tile t: issue V(t) then K(t+1) at the TOP (order pinned by sched_barrier);
// QK^T; softmax; lgkmcnt(0) + vmcnt(4) [V landed, K(t+1) still in flight] +
// raw s_barrier; PV; vmcnt(0) [K landed ~free, issued a full tile ago] + s_barrier.
// vmcnt is a per-wave FIFO in issue order; the r7/8 NaNs were the (now-fixed)
// gload_lds offset bug, not this schedule.
__global__ __launch_bounds__(256, 2) void k_attn(
    const bf16_t* __restrict__ Qw, const bf16_t* __restrict__ Kw,
    const bf16_t* __restrict__ Vw, bf16_t* __restrict__ AO) {
    __shared__ bf16_t smem[32768];               // 64 KB
    bf16_t* KtF0 = smem;                         // K buf0 [64][128] swz
    bf16_t* KtF1 = smem + 8192;                  // K buf1
    bf16_t* VtF  = smem + 16384;                 // V^T [128][64] swz
    bf16_t* PbF  = smem + 24576;                 // P [128][64] swz

    const int tid = threadIdx.x;
    const int w = tid >> 6, lane = tid & 63, c = lane & 15, g = lane >> 4;
    const int cm = c & 7;

    const int f = blockIdx.x;                    // bijective XCD swizzle (512 % 8 == 0)
    const int wid = (f & 7) * 64 + (f >> 3);
    const int bh = wid >> 4, q0 = (wid & 15) * 128;

    const bf16_t* Qb = Qw + (size_t)bh * Ss * Dd;
    const bf16_t* Kb = Kw + (size_t)bh * Ss * Dd;
    const bf16_t* Vb = Vw + (size_t)bh * Dd * Ss;

    bf16x8 qlo[4], qhi[4];
    const int qrl = q0 + w * 32 + c, qrh = qrl + 16;
#pragma unroll
    for (int kb = 0; kb < 4; kb++) {
        qlo[kb] = *reinterpret_cast<const bf16x8*>(&Qb[(size_t)qrl * Dd + kb * 32 + g * 8]);
        qhi[kb] = *reinterpret_cast<const bf16x8*>(&Qb[(size_t)qrh * Dd + kb * 32 + g * 8]);
    }

    f32x4 aolo[8], aohi[8];
#pragma unroll
    for (int i = 0; i < 8; i++) { aolo[i] = f32x4{0.f,0.f,0.f,0.f}; aohi[i] = f32x4{0.f,0.f,0.f,0.f}; }
    float m_lo = -1e30f, l_lo = 0.f, m_hi = -1e30f, l_hi = 0.f;

    // staging lane geometry: gload_lds puts lane L at LDS base + 16*L.
    const int krl = lane >> 4;                          // 0..3
    const int kc0 = ((lane & 15) ^ krl) * 8;            // swizzle-source col, rows r&7==krl
    const bf16_t* ke = Kb + (w * 16 + krl) * 128 + kc0;          // rows +0, +8
    const bf16_t* ko = Kb + (w * 16 + krl) * 128 + (kc0 ^ 32);   // rows +4, +12 (key krl^4)
    const int vrl = lane >> 3;                          // 0..7
    const int vc0 = ((lane & 7) ^ vrl) * 8;
    const bf16_t* vsrc = Vb + (w * 32 + vrl) * 2048 + vc0;

    // wave-uniform LDS bases, forced scalar
    const unsigned wq = __builtin_amdgcn_readfirstlane((unsigned)(w * 2048));
    bf16_t* kd0 = KtF0 + wq;
    bf16_t* kd1 = KtF1 + wq;
    bf16_t* vd  = VtF  + wq;

    // prologue: K(0) -> buf0, full drain + barrier
    GLOAD16(ke,        kd0);
    GLOAD16(ko + 512,  kd0 + 512);     // +4 rows
    GLOAD16(ke + 1024, kd0 + 1024);    // +8 rows
    GLOAD16(ko + 1536, kd0 + 1536);    // +12 rows
    ke += 8192; ko += 8192;
    asm volatile("s_waitcnt vmcnt(0)" ::: "memory");
    __syncthreads();

    for (int t = 0; t < 32; ++t) {
        // issue V(t) — the 4 OLDEST in-flight loads (order pinned below)
        GLOAD16(vsrc,         vd);
        GLOAD16(vsrc + 16384, vd + 512);    // +8 V rows
        GLOAD16(vsrc + 32768, vd + 1024);   // +16
        GLOAD16(vsrc + 49152, vd + 1536);   // +24
        vsrc += 64;
        __builtin_amdgcn_sched_barrier(0);  // pin: V group issues before K group
        // issue K(t+1) into the other buffer — full tile to land
        if (t < 31) {
            bf16_t* kd = (t & 1) ? kd0 : kd1;
            GLOAD16(ke,        kd);
            GLOAD16(ko + 512,  kd + 512);
            GLOAD16(ke + 1024, kd + 1024);
            GLOAD16(ko + 1536, kd + 1536);
            ke += 8192; ko += 8192;
        }
        __builtin_amdgcn_sched_barrier(0);  // pin: all DMA issued before compute

        // ---- QK^T from K buf[t&1] ----
        const bf16_t* kr = (t & 1) ? KtF1 : KtF0;
        f32x4 slo[4], shi[4];
#pragma unroll
        for (int nb = 0; nb < 4; nb++) { slo[nb] = f32x4{0.f,0.f,0.f,0.f}; shi[nb] = f32x4{0.f,0.f,0.f,0.f}; }
        __builtin_amdgcn_s_setprio(1);
#pragma unroll
        for (int kb = 0; kb < 4; kb++)
#pragma unroll
            for (int nb = 0; nb < 4; nb++) {
                bf16x8 kf = *reinterpret_cast<const bf16x8*>(
                    &kr[(nb * 16 + c) * 128 + ((4 * kb + g) ^ cm) * 8]);
                slo[nb] = MFMA16(kf, qlo[kb], slo[nb]);
                shi[nb] = MFMA16(kf, qhi[kb], shi[nb]);
            }
        __builtin_amdgcn_s_setprio(0);

        // ---- online softmax (exp2 domain) ----
        SOFTMAX_HALF(slo, m_lo, l_lo, aolo, w * 32 + c);
        SOFTMAX_HALF(shi, m_hi, l_hi, aohi, w * 32 + 16 + c);

        // P writes done; V(t) drained via counted vmcnt (K(t+1) keeps flying);
        // raw barrier (no implicit drain)
        asm volatile("s_waitcnt lgkmcnt(0)" ::: "memory");
        if (t < 31) asm volatile("s_waitcnt vmcnt(4)" ::: "memory");
        else        asm volatile("s_waitcnt vmcnt(0)" ::: "memory");
        __builtin_amdgcn_s_barrier();
        __builtin_amdgcn_sched_barrier(0);

        // ---- PV ----
        bf16x8 plo[2], phi[2];
#pragma unroll
        for (int kb2 = 0; kb2 < 2; kb2++) {
            plo[kb2] = *reinterpret_cast<const bf16x8*>(
                &PbF[(w * 32 + c) * 64 + ((4 * kb2 + g) ^ cm) * 8]);
            phi[kb2] = *reinterpret_cast<const bf16x8*>(
                &PbF[(w * 32 + 16 + c) * 64 + ((4 * kb2 + g) ^ cm) * 8]);
        }
        __builtin_amdgcn_s_setprio(1);
#pragma unroll
        for (int db = 0; db < 8; db++)
#pragma unroll
            for (int kb2 = 0; kb2 < 2; kb2++) {
                bf16x8 vf = *reinterpret_cast<const bf16x8*>(
                    &VtF[(db * 16 + c) * 64 + ((4 * kb2 + g) ^ cm) * 8]);
                aolo[db] = MFMA16(plo[kb2], vf, aolo[db]);
                aohi[db] = MFMA16(phi[kb2], vf, aohi[db]);
            }
        __builtin_amdgcn_s_setprio(0);

        // K(t+1) landed (issued a full tile ago -> near-free); all waves done
        // with buf[t&1] + V
        asm volatile("s_waitcnt vmcnt(0)" ::: "memory");
        __builtin_amdgcn_s_barrier();
        __builtin_amdgcn_sched_barrier(0);
    }

    // epilogue: reduce l, normalize, coalesced write
    l_lo += __shfl_xor(l_lo, 16); l_lo += __shfl_xor(l_lo, 32);
    l_hi += __shfl_xor(l_hi, 16); l_hi += __shfl_xor(l_hi, 32);
    float ilo = 1.0f / l_lo, ihi = 1.0f / l_hi;
    bf16_t (*Os)[136] = reinterpret_cast<bf16_t(*)[136]>(smem);
#pragma unroll
    for (int r = 0; r < 4; r++) {
        float i4l = __shfl(ilo, g * 4 + r);
        float i4h = __shfl(ihi, g * 4 + r);
        int rowl = w * 32 + g * 4 + r, rowh = rowl + 16;
#pragma unroll
        for (int db = 0; db < 8; db++) {
            Os[rowl][db * 16 + c] = (bf16_t)(aolo[db][r] * i4l);
            Os[rowh][db * 16 + c] = (bf16_t)(aohi[db][r] * i4h);
        }
    }
    __syncthreads();
    const int b = bh >> 4, h = bh & 15;
#pragma unroll
    for (int i = 0; i < 8; i++) {
        int e = tid + i * 256; int row = e >> 4, col = (e & 15) * 8;
        *reinterpret_cast<uint4*>(&AO[((size_t)(b * Ss + q0 + row)) * DH + h * Dd + col]) =
            *reinterpret_cast<const uint4*>(&Os[row][col]);
    }
}

// ---------------- output projection v5: 512 blocks x 4 waves, 4 acc chains ----------------
__global__ __launch_bounds__(256) void k_outproj(
    const bf16_t* __restrict__ A, const bf16_t* __restrict__ Wot,
    const float* __restrict__ bo, float* __restrict__ out) {
    const int tid = threadIdx.x;
    const int w = tid >> 6, lane = tid & 63, c = lane & 15, g = lane >> 4;
    const int mt = blockIdx.x >> 1, nh = blockIdx.x & 1;
    const int m0 = mt * 16;
    const int nb = nh * 4 + w;                 // global 16-col block, 0..7

    f32x4 a0 = f32x4{0.f,0.f,0.f,0.f}, a1 = f32x4{0.f,0.f,0.f,0.f};
    f32x4 a2 = f32x4{0.f,0.f,0.f,0.f}, a3 = f32x4{0.f,0.f,0.f,0.f};

    const bf16_t* Ab = A   + (size_t)(m0 + c) * DH + g * 8;
    const bf16_t* Bw = Wot + (size_t)(nb * 16 + c) * DH + g * 8;

#pragma unroll 4
    for (int kk = 0; kk < 64; kk += 4) {
        bf16x8 af0  = *reinterpret_cast<const bf16x8*>(Ab + (kk + 0) * 32);
        bf16x8 bf0  = *reinterpret_cast<const bf16x8*>(Bw + (kk + 0) * 32);
        bf16x8 af1  = *reinterpret_cast<const bf16x8*>(Ab + (kk + 1) * 32);
        bf16x8 bf1  = *reinterpret_cast<const bf16x8*>(Bw + (kk + 1) * 32);
        bf16x8 af2  = *reinterpret_cast<const bf16x8*>(Ab + (kk + 2) * 32);
        bf16x8 bf2  = *reinterpret_cast<const bf16x8*>(Bw + (kk + 2) * 32);
        bf16x8 af3  = *reinterpret_cast<const bf16x8*>(Ab + (kk + 3) * 32);
        bf16x8 bf3  = *reinterpret_cast<const bf16x8*>(Bw + (kk + 3) * 32);
        a0 = MFMA16(af0, bf0, a0);
        a1 = MFMA16(af1, bf1, a1);
        a2 = MFMA16(af2, bf2, a2);
        a3 = MFMA16(af3, bf3, a3);
    }

    f32x4 acc = (a0 + a1) + (a2 + a3);

    float bs = bo[nb * 16 + c];
#pragma unroll
    for (int r = 0; r < 4; r++)
        out[(size_t)(m0 + g * 4 + r) * Dd + nb * 16 + c] = acc[r] + bs;
}

// ---------------- launcher ----------------
extern "C" void kernel_launch(void* const* d_in, const int* in_sizes, int n_in,
                              void* d_out, int out_size, void* d_ws, size_t ws_size,
                              hipStream_t stream) {
    const float* x  = (const float*)d_in[0];
    const float* Wq = (const float*)d_in[1];
    const float* bq = (const float*)d_in[2];
    const float* Wk = (const float*)d_in[3];
    const float* bk = (const float*)d_in[4];
    const float* Wv = (const float*)d_in[5];
    const float* bv = (const float*)d_in[6];
    const float* Wo = (const float*)d_in[7];
    const float* bo = (const float*)d_in[8];
    float* out = (float*)d_out;

    char* ws = (char*)d_ws;
    bf16_t* xb  = (bf16_t*)(ws);
    bf16_t* Wt  = (bf16_t*)(ws + 1048576);
    bf16_t* Wot = (bf16_t*)(ws + 2621440);
    bf16_t* Qw  = (bf16_t*)(ws + 3145728);
    bf16_t* Kw  = (bf16_t*)(ws + 3145728 + 16777216);
    bf16_t* Vw  = (bf16_t*)(ws + 3145728 + 2 * 16777216);
    bf16_t* AO  = (bf16_t*)(ws + 3145728 + 3 * 16777216);

    k_prep<<<1536, 256, 0, stream>>>(x, Wq, Wk, Wv, Wo, xb, Wt, Wot);
    k_qkv<<<dim3(32, 16, 3), 256, 0, stream>>>(xb, Wt, bq, bk, bv, Qw, Kw, Vw);
    k_attn<<<512, 256, 0, stream>>>(Qw, Kw, Vw, AO);
    k_outproj<<<512, 256, 0, stream>>>(AO, Wot, bo, out);
}

// Round 19
// 144.965 us; speedup vs baseline: 1.2431x; 1.0420x over previous
//
#include <hip/hip_runtime.h>
#include <cstdint>
#include <cstddef>

typedef __bf16 bf16_t;
typedef bf16_t bf16x8 __attribute__((ext_vector_type(8)));
typedef bf16_t bf16x4 __attribute__((ext_vector_type(4)));
typedef float  f32x4  __attribute__((ext_vector_type(4)));

#define MFMA16(a, b, c) __builtin_amdgcn_mfma_f32_16x16x32_bf16((a), (b), (c), 0, 0, 0)

// async global->LDS DMA, 16B/lane; LDS dest = wave-uniform base + lane*16.
// offset is ALWAYS 0 (the imm offset does NOT apply to the global address on the
// LDS-DMA path — round-10/11 lesson) — all offsets baked into pointers.
#define GLOAD16(GP, LP)                                                           \
    __builtin_amdgcn_global_load_lds(                                             \
        (const __attribute__((address_space(1))) unsigned int*)(GP),              \
        (__attribute__((address_space(3))) unsigned int*)(LP), 16, 0, 0)

static constexpr int Bb = 2, Ss = 2048, Hh = 16, Dd = 128, DH = 2048;
// 1/sqrt(128) * log2(e): softmax runs in the exp2 domain (native v_exp_f32)
static constexpr float QSCALE = 0.08838834764831845f * 1.4426950408889634f;

// ---------------- merged prep: x->bf16 convert + 4 weight transposes ----------------
__global__ __launch_bounds__(256) void k_prep(
    const float* __restrict__ x,
    const float* __restrict__ Wq, const float* __restrict__ Wk,
    const float* __restrict__ Wv, const float* __restrict__ Wo,
    bf16_t* __restrict__ xb, bf16_t* __restrict__ Wt, bf16_t* __restrict__ Wot) {
    __shared__ float t[32][33];
    const int tid = threadIdx.x;
    const int bid = blockIdx.x;
    if (bid < 512) {
        int i = (bid * 256 + tid) * 4;
        float4 v = *reinterpret_cast<const float4*>(x + i);
        bf16x4 o;
        o[0] = (bf16_t)v.x; o[1] = (bf16_t)v.y; o[2] = (bf16_t)v.z; o[3] = (bf16_t)v.w;
        *reinterpret_cast<bf16x4*>(xb + i) = o;
        return;
    }
    const int u = bid - 512, m = u >> 8, tt = u & 255;
    const float* src; bf16_t* dst; int R, C, bx, by;
    if (m < 3) { src = (m == 0) ? Wq : (m == 1) ? Wk : Wv; dst = Wt + (size_t)m * 262144;
                 R = 128;  C = 2048; bx = tt & 63, by = tt >> 6; }
    else       { src = Wo; dst = Wot;
                 R = 2048; C = 128;  bx = tt & 3,  by = tt >> 2; }
    const int tx = tid & 31, ty = tid >> 5;
    const int c0 = bx * 32, r0 = by * 32;
#pragma unroll
    for (int i = 0; i < 4; i++)
        t[ty + i * 8][tx] = src[(size_t)(r0 + ty + i * 8) * C + c0 + tx];
    __syncthreads();
#pragma unroll
    for (int i = 0; i < 4; i++)
        dst[(size_t)(c0 + ty + i * 8) * R + r0 + tx] = (bf16_t)t[tx][ty + i * 8];
}

// ---------------- QKV projection GEMM: W staged once (swizzled), A direct from global ----------------
__global__ __launch_bounds__(256) void k_qkv(
    const bf16_t* __restrict__ xb, const bf16_t* __restrict__ Wt,
    const float* __restrict__ bq, const float* __restrict__ bk, const float* __restrict__ bv,
    bf16_t* __restrict__ Qw, bf16_t* __restrict__ Kw, bf16_t* __restrict__ Vw) {
    __shared__ bf16_t smem[17408];                 // Bs uses first 16384; epilogue reuses all
    bf16_t* Bs = smem;                             // [128 n][128 k] XOR-swizzled 16B blocks

    const int tid = threadIdx.x;
    const int w = tid >> 6, lane = tid & 63, c = lane & 15, g = lane >> 4;
    const int cm = c & 7;
    const int m0 = blockIdx.x * 128, n0g = blockIdx.y * 128, z = blockIdx.z;
    const bf16_t* Wz = Wt + (size_t)z * DH * Dd;
    const int wm = w * 32;

    // stage full W-tile once: 128x128 bf16, dest block ^= (row&7)
#pragma unroll
    for (int i = 0; i < 8; i++) {
        int e = tid + i * 256; int row = e >> 4, bg = e & 15;
        *reinterpret_cast<uint4*>(&Bs[row * 128 + ((bg ^ (row & 7)) * 8)]) =
            *reinterpret_cast<const uint4*>(&Wz[(size_t)(n0g + row) * 128 + bg * 8]);
    }
    __syncthreads();

    f32x4 acc[2][8];
#pragma unroll
    for (int a = 0; a < 2; a++)
#pragma unroll
        for (int b = 0; b < 8; b++) acc[a][b] = f32x4{0.f, 0.f, 0.f, 0.f};

    const int ar0 = m0 + wm + c;
#pragma unroll
    for (int kb = 0; kb < 4; kb++) {
        bf16x8 af0 = *reinterpret_cast<const bf16x8*>(&xb[(size_t)ar0 * 128 + kb * 32 + g * 8]);
        bf16x8 af1 = *reinterpret_cast<const bf16x8*>(&xb[(size_t)(ar0 + 16) * 128 + kb * 32 + g * 8]);
#pragma unroll
        for (int nb = 0; nb < 8; nb++) {
            bf16x8 bfr = *reinterpret_cast<const bf16x8*>(
                &Bs[(nb * 16 + c) * 128 + (((4 * kb + g) ^ cm) * 8)]);
            acc[0][nb] = MFMA16(af0, bfr, acc[0][nb]);
            acc[1][nb] = MFMA16(af1, bfr, acc[1][nb]);
        }
    }

    const float* bias = (z == 0) ? bq : (z == 1) ? bk : bv;
    const float sc = (z == 0) ? QSCALE : 1.0f;
    const int cstride = (z == 2) ? 131 : 136;
    __syncthreads();
#pragma unroll
    for (int mb = 0; mb < 2; mb++)
#pragma unroll
        for (int nb = 0; nb < 8; nb++) {
            float bs = bias[n0g + nb * 16 + c];
#pragma unroll
            for (int r = 0; r < 4; r++) {
                int row = wm + mb * 16 + g * 4 + r;
                int col = nb * 16 + c;
                smem[row * cstride + col] = (bf16_t)((acc[mb][nb][r] + bs) * sc);
            }
        }
    __syncthreads();
    const int h = blockIdx.y;
    if (z <= 1) {
        bf16_t* O = z ? Kw : Qw;
#pragma unroll
        for (int i = 0; i < 8; i++) {
            int e = tid + i * 256; int row = e >> 4, col = (e & 15) * 8;
            int sg = m0 + row, b = sg >> 11, s2 = sg & 2047;
            *reinterpret_cast<uint4*>(&O[(((size_t)(b * Hh + h)) * Ss + s2) * Dd + col]) =
                *reinterpret_cast<const uint4*>(&smem[row * 136 + col]);
        }
    } else {
        int b = m0 >> 11; int sbase = m0 & 2047;
        const unsigned short* cs16 = reinterpret_cast<const unsigned short*>(smem);
#pragma unroll
        for (int i = 0; i < 32; i++) {
            int e = tid + i * 256; int d = e >> 6, sl2 = (e & 63) * 2;
            unsigned int lo = cs16[sl2 * 131 + d], hi = cs16[(sl2 + 1) * 131 + d];
            unsigned int pk = lo | (hi << 16);
            *reinterpret_cast<unsigned int*>(
                &Vw[(((size_t)(b * Hh + h)) * Dd + d) * Ss + sbase + sl2]) = pk;
        }
    }
}

// ---- softmax for one 16-row q-block; writes P into XOR-swizzled PbF ----
#define SOFTMAX_HALF(SACC, M_RUN, L_RUN, AO, PROW)                                   \
    do {                                                                             \
        float pm = fmaxf(fmaxf(SACC[0][0], SACC[0][1]), fmaxf(SACC[0][2], SACC[0][3])); \
        _Pragma("unroll")                                                            \
        for (int nb = 1; nb < 4; nb++)                                               \
            _Pragma("unroll")                                                        \
            for (int r = 0; r < 4; r++) pm = fmaxf(pm, SACC[nb][r]);                 \
        pm = fmaxf(pm, __shfl_xor(pm, 16));                                          \
        pm = fmaxf(pm, __shfl_xor(pm, 32));                                          \
        if (!__all(pm <= M_RUN + 11.5f)) {                                           \
            float mn_ = fmaxf(M_RUN, pm);                                            \
            float sc_ = exp2f(M_RUN - mn_);                                          \
            M_RUN = mn_;                                                             \
            L_RUN *= sc_;                                                            \
            _Pragma("unroll")                                                        \
            for (int r = 0; r < 4; r++) {                                            \
                float s4_ = __shfl(sc_, g * 4 + r);                                  \
                _Pragma("unroll")                                                    \
                for (int db = 0; db < 8; db++) AO[db][r] *= s4_;                     \
            }                                                                        \
        }                                                                            \
        float rs_ = 0.f;                                                             \
        _Pragma("unroll")                                                            \
        for (int nb = 0; nb < 4; nb++) {                                             \
            bf16x4 pk_;                                                              \
            _Pragma("unroll")                                                        \
            for (int r = 0; r < 4; r++) {                                            \
                float pe_ = exp2f(SACC[nb][r] - M_RUN);                              \
                rs_ += pe_;                                                          \
                pk_[r] = (bf16_t)pe_;                                                \
            }                                                                        \
            *reinterpret_cast<bf16x4*>(                                              \
                &PbF[(PROW) * 64 + (((2 * nb + (g >> 1)) ^ cm) * 8) + (g & 1) * 4]) = pk_; \
        }                                                                            \
        L_RUN += rs_;                                                                \
    } while (0)

// ---------------- flash attention: round-14/16 champion structure (99 us) ----------------
// Per tile t: issue V(t); QK^T; softmax; vmcnt(0)+__syncthreads [V visible];
// issue K(t+1) into buf[~t&1]; PV; vmcnt(0)+__syncthreads [K visible].
// Each drain covers exactly one DMA group -> order-independent correctness.
__global__ __launch_bounds__(256, 2) void k_attn(
    const bf16_t* __restrict__ Qw, const bf16_t* __restrict__ Kw,
    const bf16_t* __restrict__ Vw, bf16_t* __restrict__ AO) {
    __shared__ bf16_t smem[32768];               // 64 KB
    bf16_t* KtF0 = smem;                         // K buf0 [64][128] swz
    bf16_t* KtF1 = smem + 8192;                  // K buf1
    bf16_t* VtF  = smem + 16384;                 // V^T [128][64] swz
    bf16_t* PbF  = smem + 24576;                 // P [128][64] swz

    const int tid = threadIdx.x;
    const int w = tid >> 6, lane = tid & 63, c = lane & 15, g = lane >> 4;
    const int cm = c & 7;

    const int f = blockIdx.x;                    // bijective XCD swizzle (512 % 8 == 0)
    const int wid = (f & 7) * 64 + (f >> 3);
    const int bh = wid >> 4, q0 = (wid & 15) * 128;

    const bf16_t* Qb = Qw + (size_t)bh * Ss * Dd;
    const bf16_t* Kb = Kw + (size_t)bh * Ss * Dd;
    const bf16_t* Vb = Vw + (size_t)bh * Dd * Ss;

    bf16x8 qlo[4], qhi[4];
    const int qrl = q0 + w * 32 + c, qrh = qrl + 16;
#pragma unroll
    for (int kb = 0; kb < 4; kb++) {
        qlo[kb] = *reinterpret_cast<const bf16x8*>(&Qb[(size_t)qrl * Dd + kb * 32 + g * 8]);
        qhi[kb] = *reinterpret_cast<const bf16x8*>(&Qb[(size_t)qrh * Dd + kb * 32 + g * 8]);
    }

    f32x4 aolo[8], aohi[8];
#pragma unroll
    for (int i = 0; i < 8; i++) { aolo[i] = f32x4{0.f,0.f,0.f,0.f}; aohi[i] = f32x4{0.f,0.f,0.f,0.f}; }
    float m_lo = -1e30f, l_lo = 0.f, m_hi = -1e30f, l_hi = 0.f;

    // staging lane geometry: gload_lds puts lane L at LDS base + 16*L.
    const int krl = lane >> 4;                          // 0..3
    const int kc0 = ((lane & 15) ^ krl) * 8;            // swizzle-source col, rows r&7==krl
    const bf16_t* ke = Kb + (w * 16 + krl) * 128 + kc0;          // rows +0, +8
    const bf16_t* ko = Kb + (w * 16 + krl) * 128 + (kc0 ^ 32);   // rows +4, +12 (key krl^4)
    const int vrl = lane >> 3;                          // 0..7
    const int vc0 = ((lane & 7) ^ vrl) * 8;
    const bf16_t* vsrc = Vb + (w * 32 + vrl) * 2048 + vc0;

    // wave-uniform LDS bases, forced scalar
    const unsigned wq = __builtin_amdgcn_readfirstlane((unsigned)(w * 2048));
    bf16_t* kd0 = KtF0 + wq;
    bf16_t* kd1 = KtF1 + wq;
    bf16_t* vd  = VtF  + wq;

    // prologue: K(0) -> buf0, full drain + barrier
    GLOAD16(ke,        kd0);
    GLOAD16(ko + 512,  kd0 + 512);     // +4 rows
    GLOAD16(ke + 1024, kd0 + 1024);    // +8 rows
    GLOAD16(ko + 1536, kd0 + 1536);    // +12 rows
    ke += 8192; ko += 8192;
    asm volatile("s_waitcnt vmcnt(0)" ::: "memory");
    __syncthreads();

    for (int t = 0; t < 32; ++t) {
        // issue V(t) — the only DMA in flight until the mid-tile drain
        GLOAD16(vsrc,         vd);
        GLOAD16(vsrc + 16384, vd + 512);    // +8 V rows
        GLOAD16(vsrc + 32768, vd + 1024);   // +16
        GLOAD16(vsrc + 49152, vd + 1536);   // +24
        vsrc += 64;

        // ---- QK^T from K buf[t&1] ----
        const bf16_t* kr = (t & 1) ? KtF1 : KtF0;
        f32x4 slo[4], shi[4];
#pragma unroll
        for (int nb = 0; nb < 4; nb++) { slo[nb] = f32x4{0.f,0.f,0.f,0.f}; shi[nb] = f32x4{0.f,0.f,0.f,0.f}; }
        __builtin_amdgcn_s_setprio(1);
#pragma unroll
        for (int kb = 0; kb < 4; kb++)
#pragma unroll
            for (int nb = 0; nb < 4; nb++) {
                bf16x8 kf = *reinterpret_cast<const bf16x8*>(
                    &kr[(nb * 16 + c) * 128 + ((4 * kb + g) ^ cm) * 8]);
                slo[nb] = MFMA16(kf, qlo[kb], slo[nb]);
                shi[nb] = MFMA16(kf, qhi[kb], shi[nb]);
            }
        __builtin_amdgcn_s_setprio(0);

        // ---- online softmax (exp2 domain) ----
        SOFTMAX_HALF(slo, m_lo, l_lo, aolo, w * 32 + c);
        SOFTMAX_HALF(shi, m_hi, l_hi, aohi, w * 32 + 16 + c);

        // all V DMA drained (order-independent), then full barrier
        asm volatile("s_waitcnt vmcnt(0)" ::: "memory");
        __syncthreads();

        // issue K(t+1) into the other buffer; lands during PV, drained at tile end
        if (t < 31) {
            bf16_t* kd = (t & 1) ? kd0 : kd1;
            GLOAD16(ke,        kd);
            GLOAD16(ko + 512,  kd + 512);
            GLOAD16(ke + 1024, kd + 1024);
            GLOAD16(ko + 1536, kd + 1536);
            ke += 8192; ko += 8192;
        }

        // ---- PV ----
        bf16x8 plo[2], phi[2];
#pragma unroll
        for (int kb2 = 0; kb2 < 2; kb2++) {
            plo[kb2] = *reinterpret_cast<const bf16x8*>(
                &PbF[(w * 32 + c) * 64 + ((4 * kb2 + g) ^ cm) * 8]);
            phi[kb2] = *reinterpret_cast<const bf16x8*>(
                &PbF[(w * 32 + 16 + c) * 64 + ((4 * kb2 + g) ^ cm) * 8]);
        }
        __builtin_amdgcn_s_setprio(1);
#pragma unroll
        for (int db = 0; db < 8; db++)
#pragma unroll
            for (int kb2 = 0; kb2 < 2; kb2++) {
                bf16x8 vf = *reinterpret_cast<const bf16x8*>(
                    &VtF[(db * 16 + c) * 64 + ((4 * kb2 + g) ^ cm) * 8]);
                aolo[db] = MFMA16(plo[kb2], vf, aolo[db]);
                aohi[db] = MFMA16(phi[kb2], vf, aohi[db]);
            }
        __builtin_amdgcn_s_setprio(0);

        // K(t+1) drained; everyone done with buf[t&1] + V
        asm volatile("s_waitcnt vmcnt(0)" ::: "memory");
        __syncthreads();
    }

    // epilogue: reduce l, normalize, coalesced write
    l_lo += __shfl_xor(l_lo, 16); l_lo += __shfl_xor(l_lo, 32);
    l_hi += __shfl_xor(l_hi, 16); l_hi += __shfl_xor(l_hi, 32);
    float ilo = 1.0f / l_lo, ihi = 1.0f / l_hi;
    bf16_t (*Os)[136] = reinterpret_cast<bf16_t(*)[136]>(smem);
#pragma unroll
    for (int r = 0; r < 4; r++) {
        float i4l = __shfl(ilo, g * 4 + r);
        float i4h = __shfl(ihi, g * 4 + r);
        int rowl = w * 32 + g * 4 + r, rowh = rowl + 16;
#pragma unroll
        for (int db = 0; db < 8; db++) {
            Os[rowl][db * 16 + c] = (bf16_t)(aolo[db][r] * i4l);
            Os[rowh][db * 16 + c] = (bf16_t)(aohi[db][r] * i4h);
        }
    }
    __syncthreads();
    const int b = bh >> 4, h = bh & 15;
#pragma unroll
    for (int i = 0; i < 8; i++) {
        int e = tid + i * 256; int row = e >> 4, col = (e & 15) * 8;
        *reinterpret_cast<uint4*>(&AO[((size_t)(b * Ss + q0 + row)) * DH + h * Dd + col]) =
            *reinterpret_cast<const uint4*>(&Os[row][col]);
    }
}

// ---------------- output projection v6: explicit register software pipeline ----------------
// v4/v5 compiled to VGPR=44 -> compiler serialized loads (no prefetch) -> each of
// 16 k-iterations paid full L2/L3 latency (~30 us). v6 forces one-group-ahead
// prefetch with NAMED registers: next 4 af/bf pairs load BEFORE current 4 MFMAs.
__global__ __launch_bounds__(256) void k_outproj(
    const bf16_t* __restrict__ A, const bf16_t* __restrict__ Wot,
    const float* __restrict__ bo, float* __restrict__ out) {
    const int tid = threadIdx.x;
    const int w = tid >> 6, lane = tid & 63, c = lane & 15, g = lane >> 4;
    const int mt = blockIdx.x >> 1, nh = blockIdx.x & 1;
    const int m0 = mt * 16;
    const int nb = nh * 4 + w;                 // global 16-col block, 0..7

    f32x4 a0 = f32x4{0.f,0.f,0.f,0.f}, a1 = f32x4{0.f,0.f,0.f,0.f};
    f32x4 a2 = f32x4{0.f,0.f,0.f,0.f}, a3 = f32x4{0.f,0.f,0.f,0.f};

    const bf16_t* Ab = A   + (size_t)(m0 + c) * DH + g * 8;
    const bf16_t* Bw = Wot + (size_t)(nb * 16 + c) * DH + g * 8;

    // prologue: group 0 in named regs
    bf16x8 ca0 = *reinterpret_cast<const bf16x8*>(Ab + 0 * 32);
    bf16x8 cb0 = *reinterpret_cast<const bf16x8*>(Bw + 0 * 32);
    bf16x8 ca1 = *reinterpret_cast<const bf16x8*>(Ab + 1 * 32);
    bf16x8 cb1 = *reinterpret_cast<const bf16x8*>(Bw + 1 * 32);
    bf16x8 ca2 = *reinterpret_cast<const bf16x8*>(Ab + 2 * 32);
    bf16x8 cb2 = *reinterpret_cast<const bf16x8*>(Bw + 2 * 32);
    bf16x8 ca3 = *reinterpret_cast<const bf16x8*>(Ab + 3 * 32);
    bf16x8 cb3 = *reinterpret_cast<const bf16x8*>(Bw + 3 * 32);

#pragma unroll
    for (int kk = 0; kk < 64; kk += 4) {
        bf16x8 na0, nb0, na1, nb1, na2, nb2, na3, nb3;
        if (kk + 4 < 64) {                      // prefetch next group FIRST
            na0 = *reinterpret_cast<const bf16x8*>(Ab + (kk + 4) * 32);
            nb0 = *reinterpret_cast<const bf16x8*>(Bw + (kk + 4) * 32);
            na1 = *reinterpret_cast<const bf16x8*>(Ab + (kk + 5) * 32);
            nb1 = *reinterpret_cast<const bf16x8*>(Bw + (kk + 5) * 32);
            na2 = *reinterpret_cast<const bf16x8*>(Ab + (kk + 6) * 32);
            nb2 = *reinterpret_cast<const bf16x8*>(Bw + (kk + 6) * 32);
            na3 = *reinterpret_cast<const bf16x8*>(Ab + (kk + 7) * 32);
            nb3 = *reinterpret_cast<const bf16x8*>(Bw + (kk + 7) * 32);
        }
        a0 = MFMA16(ca0, cb0, a0);
        a1 = MFMA16(ca1, cb1, a1);
        a2 = MFMA16(ca2, cb2, a2);
        a3 = MFMA16(ca3, cb3, a3);
        if (kk + 4 < 64) {
            ca0 = na0; cb0 = nb0; ca1 = na1; cb1 = nb1;
            ca2 = na2; cb2 = nb2; ca3 = na3; cb3 = nb3;
        }
    }

    f32x4 acc = (a0 + a1) + (a2 + a3);

    float bs = bo[nb * 16 + c];
#pragma unroll
    for (int r = 0; r < 4; r++)
        out[(size_t)(m0 + g * 4 + r) * Dd + nb * 16 + c] = acc[r] + bs;
}

// ---------------- launcher ----------------
extern "C" void kernel_launch(void* const* d_in, const int* in_sizes, int n_in,
                              void* d_out, int out_size, void* d_ws, size_t ws_size,
                              hipStream_t stream) {
    const float* x  = (const float*)d_in[0];
    const float* Wq = (const float*)d_in[1];
    const float* bq = (const float*)d_in[2];
    const float* Wk = (const float*)d_in[3];
    const float* bk = (const float*)d_in[4];
    const float* Wv = (const float*)d_in[5];
    const float* bv = (const float*)d_in[6];
    const float* Wo = (const float*)d_in[7];
    const float* bo = (const float*)d_in[8];
    float* out = (float*)d_out;

    char* ws = (char*)d_ws;
    bf16_t* xb  = (bf16_t*)(ws);
    bf16_t* Wt  = (bf16_t*)(ws + 1048576);
    bf16_t* Wot = (bf16_t*)(ws + 2621440);
    bf16_t* Qw  = (bf16_t*)(ws + 3145728);
    bf16_t* Kw  = (bf16_t*)(ws + 3145728 + 16777216);
    bf16_t* Vw  = (bf16_t*)(ws + 3145728 + 2 * 16777216);
    bf16_t* AO  = (bf16_t*)(ws + 3145728 + 3 * 16777216);

    k_prep<<<1536, 256, 0, stream>>>(x, Wq, Wk, Wv, Wo, xb, Wt, Wot);
    k_qkv<<<dim3(32, 16, 3), 256, 0, stream>>>(xb, Wt, bq, bk, bv, Qw, Kw, Vw);
    k_attn<<<512, 256, 0, stream>>>(Qw, Kw, Vw, AO);
    k_outproj<<<512, 256, 0, stream>>>(AO, Wot, bo, out);
}